// Round 2
// baseline (286.302 us; speedup 1.0000x reference)
//
#include <hip/hip_runtime.h>
#include <hip/hip_bf16.h>
#include <cstdint>

using f32x4    = __attribute__((ext_vector_type(4))) float;
using bf16x8_t = __attribute__((ext_vector_type(8))) __bf16;

// Problem dims
#define BATCH   128
#define NPATCH  196
#define MPAD    256     // per-image padded patch rows (BM)
#define DDIM    768
#define WCON    32
#define NCOLS   4096    // BATCH*WCON
#define BN      256
#define NBN     16      // NCOLS/BN
#define KTILES  24      // DDIM/32

// ws layout (bytes)
#define P_BYTES   (128ull*MPAD*768*2)  // padded bf16 patches
#define C_BYTES   (4096ull*768*2)      // bf16 concepts
#define F_BYTES   (128ull*768*4)       // f32 normalized cls rows
#define MAX_BYTES (128ull*4096*4)
#define P_OFF     0ull
#define C_OFF     (P_OFF + P_BYTES)
#define IMGN_OFF  (C_OFF + C_BYTES)
#define TXTN_OFF  (IMGN_OFF + F_BYTES)
#define MAX_OFF   (TXTN_OFF + F_BYTES)
#define ACC_OFF   (MAX_OFF + MAX_BYTES)
#define WS_NEED   (ACC_OFF + 256ull)

__device__ __forceinline__ ushort f2bf(float f) {
  unsigned u = __float_as_uint(f);
  unsigned r = (u + 0x7fffu + ((u >> 16) & 1u)) >> 16;
  return (ushort)r;
}

__device__ __forceinline__ void async_cp16(void* lds, const void* g) {
  __builtin_amdgcn_global_load_lds(
      (const __attribute__((address_space(1))) unsigned int*)g,
      (__attribute__((address_space(3))) unsigned int*)lds, 16, 0, 0);
}

__device__ __forceinline__ float neg_log_sigmoid(float x) {
  return (x > 0.f) ? log1pf(expf(-x)) : (log1pf(expf(x)) - x);
}

// ---------------- normalization kernels ----------------

__global__ void norm_f32_kernel(const float* __restrict__ in, float* __restrict__ out) {
  int row = blockIdx.x;
  int t = threadIdx.x; // 0..191
  const float4* ir = (const float4*)(in + (size_t)row * DDIM);
  float4 v = ir[t];
  float ss = v.x*v.x + v.y*v.y + v.z*v.z + v.w*v.w;
  __shared__ float sb[3];
  #pragma unroll
  for (int o = 32; o; o >>= 1) ss += __shfl_down(ss, o);
  if ((t & 63) == 0) sb[t >> 6] = ss;
  __syncthreads();
  float tot = sb[0] + sb[1] + sb[2];
  float scale = 1.0f / fmaxf(sqrtf(tot), 1e-12f);
  float4 o4 = make_float4(v.x*scale, v.y*scale, v.z*scale, v.w*scale);
  ((float4*)(out + (size_t)row * DDIM))[t] = o4;
}

// one row per block; rows r >= rin are zero padding
__global__ void norm_bf16_kernel(const float* __restrict__ in, ushort* __restrict__ out,
                                 int rin, int rout) {
  int bid = blockIdx.x;
  int img = bid / rout;
  int r = bid - img * rout;
  int t = threadIdx.x; // 0..191
  ushort4* orow = (ushort4*)(out + (size_t)bid * DDIM);
  if (r >= rin) { orow[t] = make_ushort4(0,0,0,0); return; }
  const float4* ir = (const float4*)(in + ((size_t)img * rin + r) * DDIM);
  float4 v = ir[t];
  float ss = v.x*v.x + v.y*v.y + v.z*v.z + v.w*v.w;
  __shared__ float sb[3];
  #pragma unroll
  for (int o = 32; o; o >>= 1) ss += __shfl_down(ss, o);
  if ((t & 63) == 0) sb[t >> 6] = ss;
  __syncthreads();
  float tot = sb[0] + sb[1] + sb[2];
  float scale = 1.0f / fmaxf(sqrtf(tot), 1e-12f);
  orow[t] = make_ushort4(f2bf(v.x*scale), f2bf(v.y*scale), f2bf(v.z*scale), f2bf(v.w*scale));
}

// ---------------- RC GEMM + column max ----------------
// Block: image bm = bid>>4, col chunk bn = bid&15 (256 concept cols).
// 256x256 tile, BK=32, 24 K-tiles. 8 waves (2Mx4N), wave tile 128x64.
// 4-deep LDS pipeline (4 x 32KB), counted vmcnt(12), raw s_barrier.
__global__ __launch_bounds__(512, 2)
void rc_gemm_max_kernel(const ushort* __restrict__ patches,
                        const ushort* __restrict__ concepts,
                        float* __restrict__ Max) {
  __shared__ __align__(16) char lds[4 * 32768];
  __shared__ float colmax[2][256];

  const int bid = blockIdx.x;
  const int bm = bid >> 4;
  const int bn = bid & 15;
  const int tid = threadIdx.x;
  const int lane = tid & 63;
  const int wid = tid >> 6;
  const int wm = wid >> 2;   // 0..1
  const int wn = wid & 3;    // 0..3

  const ushort* Ab = patches  + (size_t)bm * (MPAD * DDIM);
  const ushort* Bb = concepts + (size_t)bn * (BN * DDIM);

  // per-thread ds_read byte offsets within a buffer (quad-XOR swizzled)
  int a_off[8], b_off[4];
  #pragma unroll
  for (int i = 0; i < 8; ++i) {
    int row = wm*128 + i*16 + (lane & 15);
    int slot = (lane >> 4) ^ ((row >> 1) & 3);
    a_off[i] = row*64 + slot*16;
  }
  #pragma unroll
  for (int j = 0; j < 4; ++j) {
    int col = wn*64 + j*16 + (lane & 15);
    int slot = (lane >> 4) ^ ((col >> 1) & 3);
    b_off[j] = 16384 + col*64 + slot*16;
  }

  f32x4 acc[8][4];
  #pragma unroll
  for (int i = 0; i < 8; ++i)
    #pragma unroll
    for (int j = 0; j < 4; ++j) {
      f32x4 z = {0.f, 0.f, 0.f, 0.f};
      acc[i][j] = z;
    }

  // staging: tile t -> buffer t&3. 2048 16B chunks: c = tid + k*512.
  // k=0,1 -> A (c in [0,1024)), k=2,3 -> B. LDS dest linear, global src pre-swizzled.
  auto stage = [&](int t) {
    const int p = t & 3;
    const int k0 = t * 32;
    char* lb = lds + p * 32768;
    #pragma unroll
    for (int k = 0; k < 2; ++k) {
      int c = tid + k*512;               // A chunk
      int r = c >> 2;
      int q = (c & 3) ^ ((r >> 1) & 3);
      async_cp16(lb + c*16, Ab + (size_t)r*DDIM + k0 + q*8);
    }
    #pragma unroll
    for (int k = 0; k < 2; ++k) {
      int c = tid + k*512;               // B chunk
      int r = c >> 2;
      int q = (c & 3) ^ ((r >> 1) & 3);
      async_cp16(lb + 16384 + c*16, Bb + (size_t)r*DDIM + k0 + q*8);
    }
  };

  auto compute = [&](int p) {
    const char* lb = lds + p * 32768;
    bf16x8_t a[8], b[4];
    #pragma unroll
    for (int i = 0; i < 8; ++i) a[i] = *(const bf16x8_t*)(lb + a_off[i]);
    #pragma unroll
    for (int j = 0; j < 4; ++j) b[j] = *(const bf16x8_t*)(lb + b_off[j]);
    __builtin_amdgcn_s_setprio(1);
    #pragma unroll
    for (int i = 0; i < 8; ++i)
      #pragma unroll
      for (int j = 0; j < 4; ++j)
        acc[i][j] = __builtin_amdgcn_mfma_f32_16x16x32_bf16(a[i], b[j], acc[i][j], 0, 0, 0);
    __builtin_amdgcn_s_setprio(0);
  };

  // prologue: 3 tiles in flight
  stage(0); stage(1); stage(2);

  // main loop: stage t+3, wait tile t (12 = 3 tiles x 4 loads/wave in flight)
  for (int t = 0; t < KTILES - 3; ++t) {
    stage(t + 3);
    asm volatile("s_waitcnt vmcnt(12)" ::: "memory");
    __builtin_amdgcn_s_barrier();
    __builtin_amdgcn_sched_barrier(0);
    compute(t & 3);
    __builtin_amdgcn_sched_barrier(0);
    __builtin_amdgcn_s_barrier();   // all reads of buf t&3 done before stage(t+4)
  }
  // tail: drain 8 -> 4 -> 0
  asm volatile("s_waitcnt vmcnt(8)" ::: "memory");
  __builtin_amdgcn_s_barrier();
  __builtin_amdgcn_sched_barrier(0);
  compute((KTILES - 3) & 3);
  asm volatile("s_waitcnt vmcnt(4)" ::: "memory");
  __builtin_amdgcn_s_barrier();
  __builtin_amdgcn_sched_barrier(0);
  compute((KTILES - 2) & 3);
  asm volatile("s_waitcnt vmcnt(0)" ::: "memory");
  __builtin_amdgcn_s_barrier();
  __builtin_amdgcn_sched_barrier(0);
  compute((KTILES - 1) & 3);

  // epilogue: masked column max. D frag: col = lane&15, row = (lane>>4)*4 + e
  float cmax[4] = {-3e38f, -3e38f, -3e38f, -3e38f};
  int rbase = wm*128 + (lane >> 4)*4;
  #pragma unroll
  for (int i = 0; i < 8; ++i) {
    #pragma unroll
    for (int e = 0; e < 4; ++e) {
      if (rbase + i*16 + e < NPATCH) {
        #pragma unroll
        for (int j = 0; j < 4; ++j) cmax[j] = fmaxf(cmax[j], acc[i][j][e]);
      }
    }
  }
  #pragma unroll
  for (int j = 0; j < 4; ++j) {
    cmax[j] = fmaxf(cmax[j], __shfl_xor(cmax[j], 16));
    cmax[j] = fmaxf(cmax[j], __shfl_xor(cmax[j], 32));
  }
  if (lane < 16) {
    #pragma unroll
    for (int j = 0; j < 4; ++j) colmax[wm][wn*64 + j*16 + lane] = cmax[j];
  }
  __syncthreads();
  if (tid < 256) {
    Max[(size_t)bm * NCOLS + (size_t)bn * BN + tid] = fmaxf(colmax[0][tid], colmax[1][tid]);
  }
}

// ---------------- losses ----------------

__global__ void it_loss_kernel(const float* __restrict__ imgn, const float* __restrict__ txtn,
                               const float* __restrict__ sc, const float* __restrict__ bi,
                               float* __restrict__ acc) {
  int m = blockIdx.x;
  int c = threadIdx.x;  // 128 threads
  __shared__ __align__(16) float arow[DDIM];
  for (int k = c; k < DDIM; k += 128) arow[k] = imgn[(size_t)m * DDIM + k];
  __syncthreads();
  const float4* br = (const float4*)(txtn + (size_t)c * DDIM);
  const float4* ar = (const float4*)arow;
  float dot = 0.f;
  #pragma unroll 8
  for (int k = 0; k < DDIM/4; ++k) {
    float4 x = ar[k], y = br[k];
    dot += x.x*y.x + x.y*y.y + x.z*y.z + x.w*y.w;
  }
  float t = expf(fminf(fmaxf(sc[0], -10.f), 10.f));
  float logit = fminf(fmaxf(t*dot + bi[0], -50.f), 50.f);
  float x = (c == m) ? logit : -logit;
  float v = neg_log_sigmoid(x);
  __shared__ float sb[2];
  #pragma unroll
  for (int o = 32; o; o >>= 1) v += __shfl_down(v, o);
  if ((c & 63) == 0) sb[c >> 6] = v;
  __syncthreads();
  if (c == 0) atomicAdd(acc, sb[0] + sb[1]);
}

__global__ void rc_loss_kernel(const float* __restrict__ Max, const int* __restrict__ counts,
                               const float* __restrict__ sc, const float* __restrict__ bi,
                               float* __restrict__ acc) {
  int m = blockIdx.x;
  int v = threadIdx.x;  // 128 threads
  const float* row = Max + (size_t)m * NCOLS + (size_t)v * WCON;
  int cnt = counts[v];
  float s = 0.f;
  for (int w = 0; w < cnt; ++w) s += row[w];
  float S = s / (float)cnt;
  float t = expf(fminf(fmaxf(sc[0], -10.f), 10.f));
  float logit = fminf(fmaxf(t*S + bi[0], -50.f), 50.f);
  float x = (v == m) ? logit : -logit;
  float val = neg_log_sigmoid(x);
  __shared__ float sb[2];
  #pragma unroll
  for (int o = 32; o; o >>= 1) val += __shfl_down(val, o);
  if ((v & 63) == 0) sb[v >> 6] = val;
  __syncthreads();
  if (v == 0) atomicAdd(acc, sb[0] + sb[1]);
}

__global__ void finalize_kernel(const float* __restrict__ acc, float* __restrict__ out) {
  if (threadIdx.x == 0 && blockIdx.x == 0) {
    float it = acc[0] * (1.f / 16384.f);
    float rc = acc[1] * (1.f / 16384.f);
    out[0] = it + 0.5f * rc;
    out[1] = it;
    out[2] = rc;
  }
}

// ---------------- launch ----------------

extern "C" void kernel_launch(void* const* d_in, const int* in_sizes, int n_in,
                              void* d_out, int out_size, void* d_ws, size_t ws_size,
                              hipStream_t stream) {
  const float* image_features        = (const float*)d_in[0];
  const float* text_features         = (const float*)d_in[1];
  const float* image_token_features  = (const float*)d_in[2];
  const float* concept_text_features = (const float*)d_in[3];
  const int*   concept_counts        = (const int*)d_in[4];
  const float* logit_scale           = (const float*)d_in[5];
  const float* logit_bias            = (const float*)d_in[6];
  float* out = (float*)d_out;

  if (ws_size < WS_NEED) {
    hipMemsetAsync(d_out, 0, (size_t)out_size * sizeof(float), stream);
    return;
  }

  char* ws = (char*)d_ws;
  ushort* patches  = (ushort*)(ws + P_OFF);
  ushort* concepts = (ushort*)(ws + C_OFF);
  float*  imgn     = (float*)(ws + IMGN_OFF);
  float*  txtn     = (float*)(ws + TXTN_OFF);
  float*  Maxbuf   = (float*)(ws + MAX_OFF);
  float*  acc      = (float*)(ws + ACC_OFF);

  hipMemsetAsync(acc, 0, 2 * sizeof(float), stream);

  norm_f32_kernel<<<BATCH, 192, 0, stream>>>(image_features, imgn);
  norm_f32_kernel<<<BATCH, 192, 0, stream>>>(text_features, txtn);
  norm_bf16_kernel<<<BATCH * MPAD, 192, 0, stream>>>(image_token_features, patches, NPATCH, MPAD);
  norm_bf16_kernel<<<NCOLS, 192, 0, stream>>>(concept_text_features, concepts, WCON, WCON);

  rc_gemm_max_kernel<<<BATCH * NBN, 512, 0, stream>>>(patches, concepts, Maxbuf);

  it_loss_kernel<<<BATCH, 128, 0, stream>>>(imgn, txtn, logit_scale, logit_bias, acc);
  rc_loss_kernel<<<BATCH, 128, 0, stream>>>(Maxbuf, concept_counts, logit_scale, logit_bias, acc + 1);
  finalize_kernel<<<1, 64, 0, stream>>>(acc, out);
}

// Round 3
// 261.130 us; speedup vs baseline: 1.0964x; 1.0964x over previous
//
#include <hip/hip_runtime.h>
#include <hip/hip_bf16.h>
#include <cstdint>

using f32x4    = __attribute__((ext_vector_type(4))) float;
using bf16x8_t = __attribute__((ext_vector_type(8))) __bf16;

// Problem dims
#define BATCH   128
#define NPATCH  196
#define MTOT    25088   // 128*196, = 98*256 exactly
#define MT      98      // M-tiles of 256
#define DDIM    768
#define WCON    32
#define NCOLS   4096    // BATCH*WCON
#define BN      256
#define NBN     16      // NCOLS/BN
#define KTILE   12      // DDIM/64
#define NS      48      // KTILE*4 half-tiles

// ws layout (bytes)
#define P_BYTES   ((size_t)MTOT*768*2)   // packed bf16 patches
#define C_BYTES   (4096ull*768*2)        // bf16 concepts
#define F_BYTES   (128ull*768*4)         // f32 normalized cls rows
#define MAX_BYTES (128ull*4096*4)        // encoded-int max buffer
#define P_OFF     0ull
#define C_OFF     (P_OFF + P_BYTES)
#define IMGN_OFF  (C_OFF + C_BYTES)
#define TXTN_OFF  (IMGN_OFF + F_BYTES)
#define MAX_OFF   (TXTN_OFF + F_BYTES)
#define ACC_OFF   (MAX_OFF + MAX_BYTES)
#define WS_NEED   (ACC_OFF + 256ull)

__device__ __forceinline__ ushort f2bf(float f) {
  unsigned u = __float_as_uint(f);
  unsigned r = (u + 0x7fffu + ((u >> 16) & 1u)) >> 16;
  return (ushort)r;
}

__device__ __forceinline__ void async_cp16(void* lds, const void* g) {
  __builtin_amdgcn_global_load_lds(
      (const __attribute__((address_space(1))) unsigned int*)g,
      (__attribute__((address_space(3))) unsigned int*)lds, 16, 0, 0);
}

__device__ __forceinline__ float neg_log_sigmoid(float x) {
  return (x > 0.f) ? log1pf(expf(-x)) : (log1pf(expf(x)) - x);
}

// monotone float<->int encoding for atomicMax on floats (no NaNs here)
__device__ __forceinline__ int encf(float f) {
  int i = __float_as_int(f);
  return i >= 0 ? i : (i ^ 0x7FFFFFFF);
}
__device__ __forceinline__ float decf(int e) {
  return __int_as_float(e >= 0 ? e : (e ^ 0x7FFFFFFF));
}

template<int VM>
__device__ __forceinline__ void vmwait() {
  asm volatile("s_waitcnt vmcnt(%0)" :: "n"(VM) : "memory");
}

// ---------------- normalization kernels ----------------

__global__ void norm_f32_kernel(const float* __restrict__ in, float* __restrict__ out) {
  int row = blockIdx.x;
  int t = threadIdx.x; // 0..191
  const float4* ir = (const float4*)(in + (size_t)row * DDIM);
  float4 v = ir[t];
  float ss = v.x*v.x + v.y*v.y + v.z*v.z + v.w*v.w;
  __shared__ float sb[3];
  #pragma unroll
  for (int o = 32; o; o >>= 1) ss += __shfl_down(ss, o);
  if ((t & 63) == 0) sb[t >> 6] = ss;
  __syncthreads();
  float tot = sb[0] + sb[1] + sb[2];
  float scale = 1.0f / fmaxf(sqrtf(tot), 1e-12f);
  float4 o4 = make_float4(v.x*scale, v.y*scale, v.z*scale, v.w*scale);
  ((float4*)(out + (size_t)row * DDIM))[t] = o4;
}

// one 768-row per block, identity row mapping (packed)
__global__ void norm_bf16_packed(const float* __restrict__ in, ushort* __restrict__ out) {
  int row = blockIdx.x;
  int t = threadIdx.x; // 0..191
  const float4* ir = (const float4*)(in + (size_t)row * DDIM);
  float4 v = ir[t];
  float ss = v.x*v.x + v.y*v.y + v.z*v.z + v.w*v.w;
  __shared__ float sb[3];
  #pragma unroll
  for (int o = 32; o; o >>= 1) ss += __shfl_down(ss, o);
  if ((t & 63) == 0) sb[t >> 6] = ss;
  __syncthreads();
  float tot = sb[0] + sb[1] + sb[2];
  float scale = 1.0f / fmaxf(sqrtf(tot), 1e-12f);
  ((ushort4*)(out + (size_t)row * DDIM))[t] =
      make_ushort4(f2bf(v.x*scale), f2bf(v.y*scale), f2bf(v.z*scale), f2bf(v.w*scale));
}

// ---------------- RC GEMM + column max (8-phase schedule) ----------------
// Packed A: 25088x768 bf16. Grid 98 M-tiles x 16 N-tiles, XCD-chunked.
// 512 threads, 8 waves (2M x 4N), wave tile 128x64, BK=64 as 2 k-halves of 32.
// LDS: 2 buffers x [A_k0|B_k0|A_k1|B_k1] x 16KB = 128KB, quad-XOR swizzled.
// Half-tile stream S_j (j=4t+h) issued at phase j-6, first read at phase j or j-1.
__global__ __launch_bounds__(512, 2)
void rc_gemm_max_kernel(const ushort* __restrict__ patches,
                        const ushort* __restrict__ concepts,
                        int* __restrict__ Max) {
  __shared__ __align__(16) char lds[2 * 65536];
  __shared__ float colmax[2][2][256];

  const int bid0 = blockIdx.x;
  const int lin = (bid0 & 7) * 196 + (bid0 >> 3);   // bijective XCD chunking (1568 = 8*196)
  const int bn = lin / 98;
  const int mt = lin - bn * 98;
  const int tid = threadIdx.x;
  const int lane = tid & 63;
  const int wid = tid >> 6;
  const int wm = wid >> 2;   // 0..1
  const int wn = wid & 3;    // 0..3
  const int brow = mt * 256;

  const ushort* Ab = patches  + (size_t)brow * DDIM;
  const ushort* Bb = concepts + (size_t)bn * BN * DDIM;

  // swizzled ds_read byte offsets within a 16KB slot (256 rows x 64B)
  int a_off[8], b_off[4];
  #pragma unroll
  for (int i = 0; i < 8; ++i) {
    int row = wm*128 + i*16 + (lane & 15);
    int slot = (lane >> 4) ^ ((row >> 1) & 3);
    a_off[i] = row*64 + slot*16;
  }
  #pragma unroll
  for (int j = 0; j < 4; ++j) {
    int col = wn*64 + j*16 + (lane & 15);
    int slot = (lane >> 4) ^ ((col >> 1) & 3);
    b_off[j] = col*64 + slot*16;
  }

  f32x4 acc[8][4];
  #pragma unroll
  for (int i = 0; i < 8; ++i)
    #pragma unroll
    for (int j = 0; j < 4; ++j) {
      f32x4 z = {0.f, 0.f, 0.f, 0.f};
      acc[i][j] = z;
    }

  // stage half-tile S_j: tile T=j>>2, h=j&3 (0=A_k0,1=B_k0,2=A_k1,3=B_k1)
  auto stageS = [&](int j) {
    if (j >= NS) return;
    const int T = j >> 2;
    const int h = j & 3;
    const int kh = h >> 1;
    char* dst = lds + ((T & 1) * 65536) + h * 16384;
    const ushort* base = (h & 1) ? Bb : Ab;
    const int kcol = T*64 + kh*32;
    #pragma unroll
    for (int k2 = 0; k2 < 2; ++k2) {
      int c = tid + k2*512;
      int r = c >> 2;
      int q = (c & 3) ^ ((r >> 1) & 3);
      async_cp16(dst + c*16, base + (size_t)r*DDIM + kcol + q*8);
    }
  };

  bf16x8_t b0, b1, b2, b3;   // B-frags held across the ih pair of phases

#define PHASE(KH, IH, READB, VM, JIDX)                                        \
  {                                                                           \
    const char* ab = lds + buf + (KH)*32768;                                  \
    bf16x8_t a0 = *(const bf16x8_t*)(ab + a_off[(IH)*4+0]);                   \
    bf16x8_t a1 = *(const bf16x8_t*)(ab + a_off[(IH)*4+1]);                   \
    bf16x8_t a2 = *(const bf16x8_t*)(ab + a_off[(IH)*4+2]);                   \
    bf16x8_t a3 = *(const bf16x8_t*)(ab + a_off[(IH)*4+3]);                   \
    if (READB) {                                                              \
      const char* bb = ab + 16384;                                            \
      b0 = *(const bf16x8_t*)(bb + b_off[0]);                                 \
      b1 = *(const bf16x8_t*)(bb + b_off[1]);                                 \
      b2 = *(const bf16x8_t*)(bb + b_off[2]);                                 \
      b3 = *(const bf16x8_t*)(bb + b_off[3]);                                 \
    }                                                                         \
    stageS(JIDX);                                                             \
    __builtin_amdgcn_sched_barrier(0);                                        \
    __builtin_amdgcn_s_barrier();                                             \
    __builtin_amdgcn_sched_barrier(0);                                        \
    __builtin_amdgcn_s_setprio(1);                                            \
    acc[(IH)*4+0][0] = __builtin_amdgcn_mfma_f32_16x16x32_bf16(a0, b0, acc[(IH)*4+0][0], 0,0,0); \
    acc[(IH)*4+0][1] = __builtin_amdgcn_mfma_f32_16x16x32_bf16(a0, b1, acc[(IH)*4+0][1], 0,0,0); \
    acc[(IH)*4+0][2] = __builtin_amdgcn_mfma_f32_16x16x32_bf16(a0, b2, acc[(IH)*4+0][2], 0,0,0); \
    acc[(IH)*4+0][3] = __builtin_amdgcn_mfma_f32_16x16x32_bf16(a0, b3, acc[(IH)*4+0][3], 0,0,0); \
    acc[(IH)*4+1][0] = __builtin_amdgcn_mfma_f32_16x16x32_bf16(a1, b0, acc[(IH)*4+1][0], 0,0,0); \
    acc[(IH)*4+1][1] = __builtin_amdgcn_mfma_f32_16x16x32_bf16(a1, b1, acc[(IH)*4+1][1], 0,0,0); \
    acc[(IH)*4+1][2] = __builtin_amdgcn_mfma_f32_16x16x32_bf16(a1, b2, acc[(IH)*4+1][2], 0,0,0); \
    acc[(IH)*4+1][3] = __builtin_amdgcn_mfma_f32_16x16x32_bf16(a1, b3, acc[(IH)*4+1][3], 0,0,0); \
    acc[(IH)*4+2][0] = __builtin_amdgcn_mfma_f32_16x16x32_bf16(a2, b0, acc[(IH)*4+2][0], 0,0,0); \
    acc[(IH)*4+2][1] = __builtin_amdgcn_mfma_f32_16x16x32_bf16(a2, b1, acc[(IH)*4+2][1], 0,0,0); \
    acc[(IH)*4+2][2] = __builtin_amdgcn_mfma_f32_16x16x32_bf16(a2, b2, acc[(IH)*4+2][2], 0,0,0); \
    acc[(IH)*4+2][3] = __builtin_amdgcn_mfma_f32_16x16x32_bf16(a2, b3, acc[(IH)*4+2][3], 0,0,0); \
    acc[(IH)*4+3][0] = __builtin_amdgcn_mfma_f32_16x16x32_bf16(a3, b0, acc[(IH)*4+3][0], 0,0,0); \
    acc[(IH)*4+3][1] = __builtin_amdgcn_mfma_f32_16x16x32_bf16(a3, b1, acc[(IH)*4+3][1], 0,0,0); \
    acc[(IH)*4+3][2] = __builtin_amdgcn_mfma_f32_16x16x32_bf16(a3, b2, acc[(IH)*4+3][2], 0,0,0); \
    acc[(IH)*4+3][3] = __builtin_amdgcn_mfma_f32_16x16x32_bf16(a3, b3, acc[(IH)*4+3][3], 0,0,0); \
    __builtin_amdgcn_s_setprio(0);                                            \
    vmwait<VM>();                                                             \
    __builtin_amdgcn_sched_barrier(0);                                        \
    __builtin_amdgcn_s_barrier();                                             \
    __builtin_amdgcn_sched_barrier(0);                                        \
  }

  // prologue: issue S_0..S_5 (3 half-tiles ahead of first consumption)
  #pragma unroll
  for (int j = 0; j < 6; ++j) stageS(j);
  vmwait<8>();   // S_0, S_1 landed
  __builtin_amdgcn_sched_barrier(0);
  __builtin_amdgcn_s_barrier();
  __builtin_amdgcn_sched_barrier(0);

  int buf;
  for (int t = 0; t < KTILE - 2; ++t) {
    buf = (t & 1) * 65536;
    PHASE(0, 0, true,  8, 4*t + 6)
    PHASE(0, 1, false, 8, 4*t + 7)
    PHASE(1, 0, true,  8, 4*t + 8)
    PHASE(1, 1, false, 8, 4*t + 9)
  }
  // t = 10 (issues S_46, S_47; then stream exhausted)
  buf = 0;
  PHASE(0, 0, true,  8, 46)
  PHASE(0, 1, false, 8, 47)
  PHASE(1, 0, true,  6, NS)
  PHASE(1, 1, false, 4, NS)
  // t = 11 (drain)
  buf = 65536;
  PHASE(0, 0, true,  2, NS)
  PHASE(0, 1, false, 0, NS)
  PHASE(1, 0, true,  0, NS)
  PHASE(1, 1, false, 0, NS)
#undef PHASE

  // epilogue: segmented column max (a wave's 128 rows span <= 2 images)
  float cmax[4][2];
  #pragma unroll
  for (int j = 0; j < 4; ++j) { cmax[j][0] = -3e38f; cmax[j][1] = -3e38f; }
  const int img0w = (brow + wm*128) / NPATCH;
  #pragma unroll
  for (int i = 0; i < 8; ++i) {
    #pragma unroll
    for (int e = 0; e < 4; ++e) {
      int g = brow + wm*128 + i*16 + (lane >> 4)*4 + e;
      int seg = (g / NPATCH) - img0w;   // 0 or 1
      #pragma unroll
      for (int j = 0; j < 4; ++j) {
        float v = acc[i][j][e];
        cmax[j][0] = (seg == 0) ? fmaxf(cmax[j][0], v) : cmax[j][0];
        cmax[j][1] = (seg == 1) ? fmaxf(cmax[j][1], v) : cmax[j][1];
      }
    }
  }
  #pragma unroll
  for (int j = 0; j < 4; ++j) {
    #pragma unroll
    for (int s = 0; s < 2; ++s) {
      float v = cmax[j][s];
      v = fmaxf(v, __shfl_xor(v, 16));
      v = fmaxf(v, __shfl_xor(v, 32));
      cmax[j][s] = v;
    }
  }
  if (lane < 16) {
    #pragma unroll
    for (int j = 0; j < 4; ++j) {
      colmax[wm][0][wn*64 + j*16 + lane] = cmax[j][0];
      colmax[wm][1][wn*64 + j*16 + lane] = cmax[j][1];
    }
  }
  __syncthreads();
  {
    int w = tid >> 8;          // 0..1
    int col = tid & 255;
    int i0 = (brow + w*128) / NPATCH;
    int i1 = (brow + w*128 + 127) / NPATCH;
    int gcol = bn*BN + col;
    atomicMax(&Max[(size_t)i0 * NCOLS + gcol], encf(colmax[w][0][col]));
    if (i1 != i0) atomicMax(&Max[(size_t)i1 * NCOLS + gcol], encf(colmax[w][1][col]));
  }
}

// ---------------- losses ----------------

__global__ void it_loss_kernel(const float* __restrict__ imgn, const float* __restrict__ txtn,
                               const float* __restrict__ sc, const float* __restrict__ bi,
                               float* __restrict__ acc) {
  int m = blockIdx.x;
  int c = threadIdx.x;  // 128 threads
  __shared__ __align__(16) float arow[DDIM];
  for (int k = c; k < DDIM; k += 128) arow[k] = imgn[(size_t)m * DDIM + k];
  __syncthreads();
  const float4* br = (const float4*)(txtn + (size_t)c * DDIM);
  const float4* ar = (const float4*)arow;
  float dot = 0.f;
  #pragma unroll 8
  for (int k = 0; k < DDIM/4; ++k) {
    float4 x = ar[k], y = br[k];
    dot += x.x*y.x + x.y*y.y + x.z*y.z + x.w*y.w;
  }
  float t = expf(fminf(fmaxf(sc[0], -10.f), 10.f));
  float logit = fminf(fmaxf(t*dot + bi[0], -50.f), 50.f);
  float x = (c == m) ? logit : -logit;
  float v = neg_log_sigmoid(x);
  __shared__ float sb[2];
  #pragma unroll
  for (int o = 32; o; o >>= 1) v += __shfl_down(v, o);
  if ((c & 63) == 0) sb[c >> 6] = v;
  __syncthreads();
  if (c == 0) atomicAdd(acc, sb[0] + sb[1]);
}

__global__ void rc_loss_kernel(const int* __restrict__ Max, const int* __restrict__ counts,
                               const float* __restrict__ sc, const float* __restrict__ bi,
                               float* __restrict__ acc) {
  int m = blockIdx.x;
  int v = threadIdx.x;  // 128 threads
  const int* row = Max + (size_t)m * NCOLS + (size_t)v * WCON;
  int cnt = counts[v];
  float s = 0.f;
  for (int w = 0; w < cnt; ++w) s += decf(row[w]);
  float S = s / (float)cnt;
  float t = expf(fminf(fmaxf(sc[0], -10.f), 10.f));
  float logit = fminf(fmaxf(t*S + bi[0], -50.f), 50.f);
  float x = (v == m) ? logit : -logit;
  float val = neg_log_sigmoid(x);
  __shared__ float sb[2];
  #pragma unroll
  for (int o = 32; o; o >>= 1) val += __shfl_down(val, o);
  if ((v & 63) == 0) sb[v >> 6] = val;
  __syncthreads();
  if (v == 0) atomicAdd(acc, sb[0] + sb[1]);
}

__global__ void finalize_kernel(const float* __restrict__ acc, float* __restrict__ out) {
  if (threadIdx.x == 0 && blockIdx.x == 0) {
    float it = acc[0] * (1.f / 16384.f);
    float rc = acc[1] * (1.f / 16384.f);
    out[0] = it + 0.5f * rc;
    out[1] = it;
    out[2] = rc;
  }
}

// ---------------- launch ----------------

extern "C" void kernel_launch(void* const* d_in, const int* in_sizes, int n_in,
                              void* d_out, int out_size, void* d_ws, size_t ws_size,
                              hipStream_t stream) {
  const float* image_features        = (const float*)d_in[0];
  const float* text_features         = (const float*)d_in[1];
  const float* image_token_features  = (const float*)d_in[2];
  const float* concept_text_features = (const float*)d_in[3];
  const int*   concept_counts        = (const int*)d_in[4];
  const float* logit_scale           = (const float*)d_in[5];
  const float* logit_bias            = (const float*)d_in[6];
  float* out = (float*)d_out;

  if (ws_size < WS_NEED) {
    hipMemsetAsync(d_out, 0, (size_t)out_size * sizeof(float), stream);
    return;
  }

  char* ws = (char*)d_ws;
  ushort* patches  = (ushort*)(ws + P_OFF);
  ushort* concepts = (ushort*)(ws + C_OFF);
  float*  imgn     = (float*)(ws + IMGN_OFF);
  float*  txtn     = (float*)(ws + TXTN_OFF);
  int*    Maxbuf   = (int*)(ws + MAX_OFF);
  float*  acc      = (float*)(ws + ACC_OFF);

  hipMemsetAsync(acc, 0, 2 * sizeof(float), stream);
  hipMemsetAsync(Maxbuf, 0x80, MAX_BYTES, stream);  // 0x80808080 < enc(any cos)

  norm_f32_kernel<<<BATCH, 192, 0, stream>>>(image_features, imgn);
  norm_f32_kernel<<<BATCH, 192, 0, stream>>>(text_features, txtn);
  norm_bf16_packed<<<MTOT, 192, 0, stream>>>(image_token_features, patches);
  norm_bf16_packed<<<NCOLS, 192, 0, stream>>>(concept_text_features, concepts);

  rc_gemm_max_kernel<<<MT * NBN, 512, 0, stream>>>(patches, concepts, Maxbuf);

  it_loss_kernel<<<BATCH, 128, 0, stream>>>(imgn, txtn, logit_scale, logit_bias, acc);
  rc_loss_kernel<<<BATCH, 128, 0, stream>>>(Maxbuf, concept_counts, logit_scale, logit_bias, acc + 1);
  finalize_kernel<<<1, 64, 0, stream>>>(acc, out);
}

// Round 4
// 257.846 us; speedup vs baseline: 1.1104x; 1.0127x over previous
//
#include <hip/hip_runtime.h>
#include <hip/hip_bf16.h>
#include <cstdint>

using f32x4    = __attribute__((ext_vector_type(4))) float;
using bf16x8_t = __attribute__((ext_vector_type(8))) __bf16;

// Problem dims
#define BATCH   128
#define NPATCH  196
#define MTOT    25088   // 128*196, = 98*256 exactly
#define MT      98      // M-tiles of 256
#define DDIM    768
#define WCON    32
#define NCOLS   4096    // BATCH*WCON
#define BN      256
#define NBN     16      // NCOLS/BN
#define NT      24      // K-tiles of 32

// ws layout (bytes)
#define P_BYTES   ((size_t)MTOT*768*2)   // packed bf16 patches
#define C_BYTES   (4096ull*768*2)        // bf16 concepts
#define F_BYTES   (128ull*768*4)         // f32 normalized cls rows
#define MAX_BYTES (128ull*4096*4)        // encoded-int max buffer
#define P_OFF     0ull
#define C_OFF     (P_OFF + P_BYTES)
#define IMGN_OFF  (C_OFF + C_BYTES)
#define TXTN_OFF  (IMGN_OFF + F_BYTES)
#define MAX_OFF   (TXTN_OFF + F_BYTES)
#define ACC_OFF   (MAX_OFF + MAX_BYTES)
#define WS_NEED   (ACC_OFF + 256ull)

__device__ __forceinline__ ushort f2bf(float f) {
  unsigned u = __float_as_uint(f);
  unsigned r = (u + 0x7fffu + ((u >> 16) & 1u)) >> 16;
  return (ushort)r;
}

__device__ __forceinline__ void async_cp16(void* lds, const void* g) {
  __builtin_amdgcn_global_load_lds(
      (const __attribute__((address_space(1))) unsigned int*)g,
      (__attribute__((address_space(3))) unsigned int*)lds, 16, 0, 0);
}

__device__ __forceinline__ float neg_log_sigmoid(float x) {
  return (x > 0.f) ? log1pf(expf(-x)) : (log1pf(expf(x)) - x);
}

// monotone float<->int encoding for atomicMax on floats (no NaNs here)
__device__ __forceinline__ int encf(float f) {
  int i = __float_as_int(f);
  return i >= 0 ? i : (i ^ 0x7FFFFFFF);
}
__device__ __forceinline__ float decf(int e) {
  return __int_as_float(e >= 0 ? e : (e ^ 0x7FFFFFFF));
}

// ---------------- normalization kernels ----------------

__global__ void norm_f32_kernel(const float* __restrict__ in, float* __restrict__ out) {
  int row = blockIdx.x;
  int t = threadIdx.x; // 0..191
  const float4* ir = (const float4*)(in + (size_t)row * DDIM);
  float4 v = ir[t];
  float ss = v.x*v.x + v.y*v.y + v.z*v.z + v.w*v.w;
  __shared__ float sb[3];
  #pragma unroll
  for (int o = 32; o; o >>= 1) ss += __shfl_down(ss, o);
  if ((t & 63) == 0) sb[t >> 6] = ss;
  __syncthreads();
  float tot = sb[0] + sb[1] + sb[2];
  float scale = 1.0f / fmaxf(sqrtf(tot), 1e-12f);
  float4 o4 = make_float4(v.x*scale, v.y*scale, v.z*scale, v.w*scale);
  ((float4*)(out + (size_t)row * DDIM))[t] = o4;
}

// one 768-row per block, identity row mapping (packed)
__global__ void norm_bf16_packed(const float* __restrict__ in, ushort* __restrict__ out) {
  int row = blockIdx.x;
  int t = threadIdx.x; // 0..191
  const float4* ir = (const float4*)(in + (size_t)row * DDIM);
  float4 v = ir[t];
  float ss = v.x*v.x + v.y*v.y + v.z*v.z + v.w*v.w;
  __shared__ float sb[3];
  #pragma unroll
  for (int o = 32; o; o >>= 1) ss += __shfl_down(ss, o);
  if ((t & 63) == 0) sb[t >> 6] = ss;
  __syncthreads();
  float tot = sb[0] + sb[1] + sb[2];
  float scale = 1.0f / fmaxf(sqrtf(tot), 1e-12f);
  ((ushort4*)(out + (size_t)row * DDIM))[t] =
      make_ushort4(f2bf(v.x*scale), f2bf(v.y*scale), f2bf(v.z*scale), f2bf(v.w*scale));
}

// ---------------- RC GEMM + column max ----------------
// Packed A: 25088x768 bf16. Grid 98 M-tiles x 16 N-tiles, bn-pair per XCD.
// 512 threads, 8 waves (2M x 4N), wave tile 128x64. BK=32, 24 K-tiles.
// 4-deep LDS pipeline (4 x [A 16KB | B 16KB]), quad-XOR swizzled.
// Per tile: 2 phases {ds_read / stage half-tile / barrier / 16 MFMA / barrier},
// one counted vmcnt(8) per tile (tile t+1 landed, t+2,t+3 in flight).
__global__ __launch_bounds__(512, 2)
void rc_gemm_max_kernel(const ushort* __restrict__ patches,
                        const ushort* __restrict__ concepts,
                        int* __restrict__ Max) {
  __shared__ __align__(16) char lds[4 * 32768];
  __shared__ float colmax[2][2][256];

  const int bid0 = blockIdx.x;
  const int lin = (bid0 & 7) * 196 + (bid0 >> 3);   // bijective (1568 = 8*196)
  const int bn = lin / 98;
  const int mt = lin - bn * 98;
  const int tid = threadIdx.x;
  const int lane = tid & 63;
  const int wid = tid >> 6;
  const int wm = wid >> 2;   // 0..1
  const int wn = wid & 3;    // 0..3
  const int brow = mt * 256;

  const ushort* Ab = patches  + (size_t)brow * DDIM;
  const ushort* Bb = concepts + (size_t)bn * BN * DDIM;

  // swizzled ds_read byte offsets within a 16KB slot (256 rows x 64B)
  int a_off[8], b_off[4];
  #pragma unroll
  for (int i = 0; i < 8; ++i) {
    int row = wm*128 + i*16 + (lane & 15);
    int slot = (lane >> 4) ^ ((row >> 1) & 3);
    a_off[i] = row*64 + slot*16;
  }
  #pragma unroll
  for (int j = 0; j < 4; ++j) {
    int col = wn*64 + j*16 + (lane & 15);
    int slot = (lane >> 4) ^ ((col >> 1) & 3);
    b_off[j] = 16384 + col*64 + slot*16;
  }

  f32x4 acc[8][4];
  #pragma unroll
  for (int i = 0; i < 8; ++i)
    #pragma unroll
    for (int j = 0; j < 4; ++j) {
      f32x4 z = {0.f, 0.f, 0.f, 0.f};
      acc[i][j] = z;
    }

  // stage half h (0=A,1=B) of K-tile t into buffer t&3; 2 x 16B per thread
  auto stageH = [&](int t, int h) {
    char* dst = lds + (t & 3) * 32768 + h * 16384;
    const ushort* base = h ? Bb : Ab;
    const int kcol = t * 32;
    #pragma unroll
    for (int k2 = 0; k2 < 2; ++k2) {
      int c = tid + k2*512;
      int r = c >> 2;
      int q = (c & 3) ^ ((r >> 1) & 3);
      async_cp16(dst + c*16, base + (size_t)r*DDIM + kcol + q*8);
    }
  };

#define MFMA16(IB, A0, A1, A2, A3)                                                          \
    acc[IB+0][0] = __builtin_amdgcn_mfma_f32_16x16x32_bf16(A0, b0, acc[IB+0][0], 0,0,0);    \
    acc[IB+0][1] = __builtin_amdgcn_mfma_f32_16x16x32_bf16(A0, b1, acc[IB+0][1], 0,0,0);    \
    acc[IB+0][2] = __builtin_amdgcn_mfma_f32_16x16x32_bf16(A0, b2, acc[IB+0][2], 0,0,0);    \
    acc[IB+0][3] = __builtin_amdgcn_mfma_f32_16x16x32_bf16(A0, b3, acc[IB+0][3], 0,0,0);    \
    acc[IB+1][0] = __builtin_amdgcn_mfma_f32_16x16x32_bf16(A1, b0, acc[IB+1][0], 0,0,0);    \
    acc[IB+1][1] = __builtin_amdgcn_mfma_f32_16x16x32_bf16(A1, b1, acc[IB+1][1], 0,0,0);    \
    acc[IB+1][2] = __builtin_amdgcn_mfma_f32_16x16x32_bf16(A1, b2, acc[IB+1][2], 0,0,0);    \
    acc[IB+1][3] = __builtin_amdgcn_mfma_f32_16x16x32_bf16(A1, b3, acc[IB+1][3], 0,0,0);    \
    acc[IB+2][0] = __builtin_amdgcn_mfma_f32_16x16x32_bf16(A2, b0, acc[IB+2][0], 0,0,0);    \
    acc[IB+2][1] = __builtin_amdgcn_mfma_f32_16x16x32_bf16(A2, b1, acc[IB+2][1], 0,0,0);    \
    acc[IB+2][2] = __builtin_amdgcn_mfma_f32_16x16x32_bf16(A2, b2, acc[IB+2][2], 0,0,0);    \
    acc[IB+2][3] = __builtin_amdgcn_mfma_f32_16x16x32_bf16(A2, b3, acc[IB+2][3], 0,0,0);    \
    acc[IB+3][0] = __builtin_amdgcn_mfma_f32_16x16x32_bf16(A3, b0, acc[IB+3][0], 0,0,0);    \
    acc[IB+3][1] = __builtin_amdgcn_mfma_f32_16x16x32_bf16(A3, b1, acc[IB+3][1], 0,0,0);    \
    acc[IB+3][2] = __builtin_amdgcn_mfma_f32_16x16x32_bf16(A3, b2, acc[IB+3][2], 0,0,0);    \
    acc[IB+3][3] = __builtin_amdgcn_mfma_f32_16x16x32_bf16(A3, b3, acc[IB+3][3], 0,0,0);

#define TILE(T, DOSTAGE, VMN)                                                 \
  {                                                                           \
    const char* ab = lds + ((T) & 3) * 32768;                                 \
    bf16x8_t a0 = *(const bf16x8_t*)(ab + a_off[0]);                          \
    bf16x8_t a1 = *(const bf16x8_t*)(ab + a_off[1]);                          \
    bf16x8_t a2 = *(const bf16x8_t*)(ab + a_off[2]);                          \
    bf16x8_t a3 = *(const bf16x8_t*)(ab + a_off[3]);                          \
    bf16x8_t b0 = *(const bf16x8_t*)(ab + b_off[0]);                          \
    bf16x8_t b1 = *(const bf16x8_t*)(ab + b_off[1]);                          \
    bf16x8_t b2 = *(const bf16x8_t*)(ab + b_off[2]);                          \
    bf16x8_t b3 = *(const bf16x8_t*)(ab + b_off[3]);                          \
    if (DOSTAGE) stageH((T) + 3, 0);                                          \
    __builtin_amdgcn_s_barrier();                                             \
    __builtin_amdgcn_s_setprio(1);                                            \
    MFMA16(0, a0, a1, a2, a3)                                                 \
    __builtin_amdgcn_s_setprio(0);                                            \
    __builtin_amdgcn_s_barrier();                                             \
    bf16x8_t a4 = *(const bf16x8_t*)(ab + a_off[4]);                          \
    bf16x8_t a5 = *(const bf16x8_t*)(ab + a_off[5]);                          \
    bf16x8_t a6 = *(const bf16x8_t*)(ab + a_off[6]);                          \
    bf16x8_t a7 = *(const bf16x8_t*)(ab + a_off[7]);                          \
    if (DOSTAGE) stageH((T) + 3, 1);                                          \
    asm volatile("s_waitcnt vmcnt(%0)" :: "n"(VMN) : "memory");               \
    __builtin_amdgcn_s_barrier();                                             \
    __builtin_amdgcn_s_setprio(1);                                            \
    MFMA16(4, a4, a5, a6, a7)                                                 \
    __builtin_amdgcn_s_setprio(0);                                            \
    __builtin_amdgcn_s_barrier();                                             \
  }

  // prologue: tiles 0,1,2 in flight; wait tile 0 (8 = tiles 1,2 outstanding)
  stageH(0, 0); stageH(0, 1);
  stageH(1, 0); stageH(1, 1);
  stageH(2, 0); stageH(2, 1);
  asm volatile("s_waitcnt vmcnt(8)" ::: "memory");
  __builtin_amdgcn_s_barrier();

  for (int t = 0; t < NT - 3; ++t) {
    TILE(t, true, 8)
  }
  TILE(NT - 3, false, 4)
  TILE(NT - 2, false, 0)
  TILE(NT - 1, false, 0)
#undef TILE
#undef MFMA16

  // epilogue: segmented column max (a wave's 128 rows span <= 2 images)
  float cmax[4][2];
  #pragma unroll
  for (int j = 0; j < 4; ++j) { cmax[j][0] = -3e38f; cmax[j][1] = -3e38f; }
  const int img0w = (brow + wm*128) / NPATCH;
  #pragma unroll
  for (int i = 0; i < 8; ++i) {
    #pragma unroll
    for (int e = 0; e < 4; ++e) {
      int g = brow + wm*128 + i*16 + (lane >> 4)*4 + e;
      int seg = (g / NPATCH) - img0w;   // 0 or 1
      #pragma unroll
      for (int j = 0; j < 4; ++j) {
        float v = acc[i][j][e];
        cmax[j][0] = (seg == 0) ? fmaxf(cmax[j][0], v) : cmax[j][0];
        cmax[j][1] = (seg == 1) ? fmaxf(cmax[j][1], v) : cmax[j][1];
      }
    }
  }
  #pragma unroll
  for (int j = 0; j < 4; ++j) {
    #pragma unroll
    for (int s = 0; s < 2; ++s) {
      float v = cmax[j][s];
      v = fmaxf(v, __shfl_xor(v, 16));
      v = fmaxf(v, __shfl_xor(v, 32));
      cmax[j][s] = v;
    }
  }
  if (lane < 16) {
    #pragma unroll
    for (int j = 0; j < 4; ++j) {
      colmax[wm][0][wn*64 + j*16 + lane] = cmax[j][0];
      colmax[wm][1][wn*64 + j*16 + lane] = cmax[j][1];
    }
  }
  __syncthreads();
  {
    int w = tid >> 8;          // 0..1
    int col = tid & 255;
    int i0 = (brow + w*128) / NPATCH;
    int i1 = (brow + w*128 + 127) / NPATCH;
    int gcol = bn*BN + col;
    atomicMax(&Max[(size_t)i0 * NCOLS + gcol], encf(colmax[w][0][col]));
    if (i1 != i0) atomicMax(&Max[(size_t)i1 * NCOLS + gcol], encf(colmax[w][1][col]));
  }
}

// ---------------- losses ----------------

__global__ void it_loss_kernel(const float* __restrict__ imgn, const float* __restrict__ txtn,
                               const float* __restrict__ sc, const float* __restrict__ bi,
                               float* __restrict__ acc) {
  int m = blockIdx.x;
  int c = threadIdx.x;  // 128 threads
  __shared__ __align__(16) float arow[DDIM];
  for (int k = c; k < DDIM; k += 128) arow[k] = imgn[(size_t)m * DDIM + k];
  __syncthreads();
  const float4* br = (const float4*)(txtn + (size_t)c * DDIM);
  const float4* ar = (const float4*)arow;
  float dot = 0.f;
  #pragma unroll 8
  for (int k = 0; k < DDIM/4; ++k) {
    float4 x = ar[k], y = br[k];
    dot += x.x*y.x + x.y*y.y + x.z*y.z + x.w*y.w;
  }
  float t = expf(fminf(fmaxf(sc[0], -10.f), 10.f));
  float logit = fminf(fmaxf(t*dot + bi[0], -50.f), 50.f);
  float x = (c == m) ? logit : -logit;
  float v = neg_log_sigmoid(x);
  __shared__ float sb[2];
  #pragma unroll
  for (int o = 32; o; o >>= 1) v += __shfl_down(v, o);
  if ((c & 63) == 0) sb[c >> 6] = v;
  __syncthreads();
  if (c == 0) atomicAdd(acc, sb[0] + sb[1]);
}

__global__ void rc_loss_kernel(const int* __restrict__ Max, const int* __restrict__ counts,
                               const float* __restrict__ sc, const float* __restrict__ bi,
                               float* __restrict__ acc) {
  int m = blockIdx.x;
  int v = threadIdx.x;  // 128 threads
  const int* row = Max + (size_t)m * NCOLS + (size_t)v * WCON;
  int cnt = counts[v];
  float s = 0.f;
  for (int w = 0; w < cnt; ++w) s += decf(row[w]);
  float S = s / (float)cnt;
  float t = expf(fminf(fmaxf(sc[0], -10.f), 10.f));
  float logit = fminf(fmaxf(t*S + bi[0], -50.f), 50.f);
  float x = (v == m) ? logit : -logit;
  float val = neg_log_sigmoid(x);
  __shared__ float sb[2];
  #pragma unroll
  for (int o = 32; o; o >>= 1) val += __shfl_down(val, o);
  if ((v & 63) == 0) sb[v >> 6] = val;
  __syncthreads();
  if (v == 0) atomicAdd(acc, sb[0] + sb[1]);
}

__global__ void finalize_kernel(const float* __restrict__ acc, float* __restrict__ out) {
  if (threadIdx.x == 0 && blockIdx.x == 0) {
    float it = acc[0] * (1.f / 16384.f);
    float rc = acc[1] * (1.f / 16384.f);
    out[0] = it + 0.5f * rc;
    out[1] = it;
    out[2] = rc;
  }
}

// ---------------- launch ----------------

extern "C" void kernel_launch(void* const* d_in, const int* in_sizes, int n_in,
                              void* d_out, int out_size, void* d_ws, size_t ws_size,
                              hipStream_t stream) {
  const float* image_features        = (const float*)d_in[0];
  const float* text_features         = (const float*)d_in[1];
  const float* image_token_features  = (const float*)d_in[2];
  const float* concept_text_features = (const float*)d_in[3];
  const int*   concept_counts        = (const int*)d_in[4];
  const float* logit_scale           = (const float*)d_in[5];
  const float* logit_bias            = (const float*)d_in[6];
  float* out = (float*)d_out;

  if (ws_size < WS_NEED) {
    hipMemsetAsync(d_out, 0, (size_t)out_size * sizeof(float), stream);
    return;
  }

  char* ws = (char*)d_ws;
  ushort* patches  = (ushort*)(ws + P_OFF);
  ushort* concepts = (ushort*)(ws + C_OFF);
  float*  imgn     = (float*)(ws + IMGN_OFF);
  float*  txtn     = (float*)(ws + TXTN_OFF);
  int*    Maxbuf   = (int*)(ws + MAX_OFF);
  float*  acc      = (float*)(ws + ACC_OFF);

  hipMemsetAsync(acc, 0, 2 * sizeof(float), stream);
  hipMemsetAsync(Maxbuf, 0x80, MAX_BYTES, stream);  // 0x80808080 < enc(any cos)

  norm_f32_kernel<<<BATCH, 192, 0, stream>>>(image_features, imgn);
  norm_f32_kernel<<<BATCH, 192, 0, stream>>>(text_features, txtn);
  norm_bf16_packed<<<MTOT, 192, 0, stream>>>(image_token_features, patches);
  norm_bf16_packed<<<NCOLS, 192, 0, stream>>>(concept_text_features, concepts);

  rc_gemm_max_kernel<<<MT * NBN, 512, 0, stream>>>(patches, concepts, Maxbuf);

  it_loss_kernel<<<BATCH, 128, 0, stream>>>(imgn, txtn, logit_scale, logit_bias, acc);
  rc_loss_kernel<<<BATCH, 128, 0, stream>>>(Maxbuf, concept_counts, logit_scale, logit_bias, acc + 1);
  finalize_kernel<<<1, 64, 0, stream>>>(acc, out);
}

// Round 5
// 169.844 us; speedup vs baseline: 1.6857x; 1.5181x over previous
//
#include <hip/hip_runtime.h>
#include <hip/hip_bf16.h>
#include <cstdint>

using i32x4 = __attribute__((ext_vector_type(4))) int;

// Problem dims
#define BATCH   128
#define NPATCH  196
#define MTOT    25088   // 128*196, = 98*256 exactly
#define MT      98      // M-tiles of 256
#define DDIM    768
#define WCON    32
#define NCOLS   4096    // BATCH*WCON
#define BNC     128     // cols per block
#define NBN     32      // NCOLS/BNC
#define NT      12      // K-tiles of 64
#define NBLK    3136    // MT*NBN

// ws layout (bytes), each 256-aligned
#define PI8_OFF   0ull
#define PI8_BYTES ((size_t)MTOT*DDIM)          // 19.3 MB
#define CI8_OFF   (PI8_OFF + PI8_BYTES)
#define CI8_BYTES (4096ull*DDIM)               // 3.1 MB
#define SP_OFF    (CI8_OFF + CI8_BYTES)
#define SP_BYTES  ((size_t)MTOT*4)
#define SC_OFF    (SP_OFF + SP_BYTES)
#define SC_BYTES  (4096ull*4)
#define IMGN_OFF  (SC_OFF + SC_BYTES)
#define F_BYTES   (128ull*768*4)
#define TXTN_OFF  (IMGN_OFF + F_BYTES)
#define MAX_OFF   (TXTN_OFF + F_BYTES)
#define MAX_BYTES (128ull*4096*4)
#define ACC_OFF   (MAX_OFF + MAX_BYTES)
#define WS_NEED   (ACC_OFF + 256ull)

__device__ __forceinline__ void async_cp16(void* lds, const void* g) {
  __builtin_amdgcn_global_load_lds(
      (const __attribute__((address_space(1))) unsigned int*)g,
      (__attribute__((address_space(3))) unsigned int*)lds, 16, 0, 0);
}

__device__ __forceinline__ float neg_log_sigmoid(float x) {
  return (x > 0.f) ? log1pf(expf(-x)) : (log1pf(expf(x)) - x);
}

// monotone float<->int encoding for atomicMax on floats (no NaNs here)
__device__ __forceinline__ int encf(float f) {
  int i = __float_as_int(f);
  return i >= 0 ? i : (i ^ 0x7FFFFFFF);
}
__device__ __forceinline__ float decf(int e) {
  return __int_as_float(e >= 0 ? e : (e ^ 0x7FFFFFFF));
}

// ---------------- normalization kernels ----------------

// f32-normalized rows for the IT path
__global__ void norm_f32_kernel(const float* __restrict__ in, float* __restrict__ out) {
  int row = blockIdx.x;
  int t = threadIdx.x; // 0..191
  const float4* ir = (const float4*)(in + (size_t)row * DDIM);
  float4 v = ir[t];
  float ss = v.x*v.x + v.y*v.y + v.z*v.z + v.w*v.w;
  __shared__ float sb[3];
  #pragma unroll
  for (int o = 32; o; o >>= 1) ss += __shfl_down(ss, o);
  if ((t & 63) == 0) sb[t >> 6] = ss;
  __syncthreads();
  float tot = sb[0] + sb[1] + sb[2];
  float scale = 1.0f / fmaxf(sqrtf(tot), 1e-12f);
  ((float4*)(out + (size_t)row * DDIM))[t] =
      make_float4(v.x*scale, v.y*scale, v.z*scale, v.w*scale);
}

// per-row: normalize + symmetric-absmax int8 quantization.
// q_k = rint(127 * x_k / absmax(x)); dequant scale srow = absmax / (127 * ||x||)
__global__ void norm_quant_i8(const float* __restrict__ in, char* __restrict__ out,
                              float* __restrict__ srow) {
  int row = blockIdx.x;
  int t = threadIdx.x; // 0..191
  const float4* ir = (const float4*)(in + (size_t)row * DDIM);
  float4 v = ir[t];
  float ss = v.x*v.x + v.y*v.y + v.z*v.z + v.w*v.w;
  float am = fmaxf(fmaxf(fabsf(v.x), fabsf(v.y)), fmaxf(fabsf(v.z), fabsf(v.w)));
  __shared__ float sbs[3], sba[3];
  #pragma unroll
  for (int o = 32; o; o >>= 1) {
    ss += __shfl_down(ss, o);
    am = fmaxf(am, __shfl_down(am, o));
  }
  if ((t & 63) == 0) { sbs[t >> 6] = ss; sba[t >> 6] = am; }
  __syncthreads();
  float tot = sbs[0] + sbs[1] + sbs[2];
  float amx = fmaxf(fmaxf(sba[0], sba[1]), fmaxf(sba[2], 1e-30f));
  float qs = 127.0f / amx;
  int qx = (int)rintf(v.x * qs), qy = (int)rintf(v.y * qs);
  int qz = (int)rintf(v.z * qs), qw = (int)rintf(v.w * qs);
  uint packed = (uint)(qx & 0xff) | ((uint)(qy & 0xff) << 8) |
                ((uint)(qz & 0xff) << 16) | ((uint)(qw & 0xff) << 24);
  ((uint*)(out + (size_t)row * DDIM))[t] = packed;
  if (t == 0) srow[row] = amx / (127.0f * fmaxf(sqrtf(tot), 1e-12f));
}

// ---------------- RC GEMM (int8) + column max ----------------
// Packed A: 25088x768 i8. Grid 98 M-tiles x 32 N-tiles.
// 256 threads, 4 waves (2M x 2N), wave tile 128x64. BK=64, 12 K-tiles.
// m97-style double-buffered global_load_lds loop (2 x 24KB), quad-XOR swizzle.
__global__ __launch_bounds__(256, 2)
void rc_gemm_max_kernel(const char* __restrict__ patches,
                        const char* __restrict__ concepts,
                        const float* __restrict__ sp,
                        const float* __restrict__ sc,
                        int* __restrict__ Max) {
  __shared__ __align__(16) char lds[2 * 24576];
  __shared__ float sp_lds[256];
  __shared__ float sc_lds[128];
  __shared__ float colmax[2][2][128];   // [wm][seg][col]

  const int bid0 = blockIdx.x;
  const int lin = (bid0 & 7) * 392 + (bid0 >> 3);  // bijective (3136 = 8*392)
  const int mt = lin >> 5;          // 0..97  (mt-major within XCD: B stays L2-hot)
  const int bn = lin & 31;
  const int tid = threadIdx.x;
  const int lane = tid & 63;
  const int wid = tid >> 6;
  const int wm = wid >> 1;   // 0..1
  const int wn = wid & 1;    // 0..1
  const int brow = mt * 256;
  const int bcol = bn * BNC;

  const char* Ab = patches  + (size_t)brow * DDIM;
  const char* Bb = concepts + (size_t)bcol * DDIM;

  // epilogue scales into LDS (used after many syncs)
  sp_lds[tid] = sp[brow + tid];
  if (tid < 128) sc_lds[tid] = sc[bcol + tid];

  // swizzled ds_read byte offsets (rows of 64B, 4 chunks of 16B, quad-XOR)
  int a_off[8], b_off[4];
  #pragma unroll
  for (int i = 0; i < 8; ++i) {
    int row = wm*128 + i*16 + (lane & 15);
    int slot = (lane >> 4) ^ ((row >> 1) & 3);
    a_off[i] = row*64 + slot*16;
  }
  #pragma unroll
  for (int j = 0; j < 4; ++j) {
    int col = wn*64 + j*16 + (lane & 15);
    int slot = (lane >> 4) ^ ((col >> 1) & 3);
    b_off[j] = 16384 + col*64 + slot*16;
  }

  i32x4 acc[8][4];
  #pragma unroll
  for (int i = 0; i < 8; ++i)
    #pragma unroll
    for (int j = 0; j < 4; ++j) {
      i32x4 z = {0, 0, 0, 0};
      acc[i][j] = z;
    }

  // stage K-tile t into buffer t&1: A 1024 chunks (16KB), B 512 chunks (8KB)
  auto stage = [&](int t) {
    char* dst = lds + (t & 1) * 24576;
    const int kcol = t * 64;
    #pragma unroll
    for (int k2 = 0; k2 < 4; ++k2) {
      int c = tid + k2*256;
      int r = c >> 2;
      int q = (c & 3) ^ ((r >> 1) & 3);
      async_cp16(dst + c*16, Ab + (size_t)r*DDIM + kcol + q*16);
    }
    #pragma unroll
    for (int k2 = 0; k2 < 2; ++k2) {
      int c = tid + k2*256;
      int r = c >> 2;
      int q = (c & 3) ^ ((r >> 1) & 3);
      async_cp16(dst + 16384 + c*16, Bb + (size_t)r*DDIM + kcol + q*16);
    }
  };

  auto compute = [&](int t) {
    const char* ab = lds + (t & 1) * 24576;
    i32x4 a[8], b[4];
    #pragma unroll
    for (int i = 0; i < 8; ++i) a[i] = *(const i32x4*)(ab + a_off[i]);
    #pragma unroll
    for (int j = 0; j < 4; ++j) b[j] = *(const i32x4*)(ab + b_off[j]);
    #pragma unroll
    for (int i = 0; i < 8; ++i)
      #pragma unroll
      for (int j = 0; j < 4; ++j)
        acc[i][j] = __builtin_amdgcn_mfma_i32_16x16x64_i8(a[i], b[j], acc[i][j], 0, 0, 0);
  };

  stage(0);
  __syncthreads();                 // tile 0 landed (sync drains vmcnt)
  for (int t = 0; t < NT; ++t) {
    if (t < NT - 1) stage(t + 1);  // in flight during compute(t)
    compute(t);
    __syncthreads();               // tile t+1 landed; buf (t&1) safe to reuse
  }

  // epilogue: dequant + segmented column max (wave's 128 rows span <= 2 images)
  float cmax[4][2];
  #pragma unroll
  for (int j = 0; j < 4; ++j) { cmax[j][0] = -3e38f; cmax[j][1] = -3e38f; }
  float scv[4];
  #pragma unroll
  for (int j = 0; j < 4; ++j) scv[j] = sc_lds[wn*64 + j*16 + (lane & 15)];
  const int img0w = (brow + wm*128) / NPATCH;
  #pragma unroll
  for (int i = 0; i < 8; ++i) {
    #pragma unroll
    for (int e = 0; e < 4; ++e) {
      int rl = wm*128 + i*16 + (lane >> 4)*4 + e;
      float spv = sp_lds[rl];
      int seg = ((brow + rl) / NPATCH) - img0w;   // 0 or 1
      #pragma unroll
      for (int j = 0; j < 4; ++j) {
        float v = (float)acc[i][j][e] * spv * scv[j];
        cmax[j][0] = (seg == 0) ? fmaxf(cmax[j][0], v) : cmax[j][0];
        cmax[j][1] = (seg == 1) ? fmaxf(cmax[j][1], v) : cmax[j][1];
      }
    }
  }
  #pragma unroll
  for (int j = 0; j < 4; ++j) {
    #pragma unroll
    for (int s = 0; s < 2; ++s) {
      float v = cmax[j][s];
      v = fmaxf(v, __shfl_xor(v, 16));
      v = fmaxf(v, __shfl_xor(v, 32));
      cmax[j][s] = v;
    }
  }
  if (lane < 16) {
    #pragma unroll
    for (int j = 0; j < 4; ++j) {
      colmax[wm][0][wn*64 + j*16 + lane] = cmax[j][0];
      colmax[wm][1][wn*64 + j*16 + lane] = cmax[j][1];
    }
  }
  __syncthreads();
  {
    int w = tid >> 7;          // 0..1 (wm)
    int col = tid & 127;
    int i0 = (brow + w*128) / NPATCH;
    int i1 = (brow + w*128 + 127) / NPATCH;
    int gcol = bcol + col;
    atomicMax(&Max[(size_t)i0 * NCOLS + gcol], encf(colmax[w][0][col]));
    if (i1 != i0) atomicMax(&Max[(size_t)i1 * NCOLS + gcol], encf(colmax[w][1][col]));
  }
}

// ---------------- losses ----------------

__global__ void it_loss_kernel(const float* __restrict__ imgn, const float* __restrict__ txtn,
                               const float* __restrict__ sc, const float* __restrict__ bi,
                               float* __restrict__ acc) {
  int m = blockIdx.x;
  int c = threadIdx.x;  // 128 threads
  __shared__ __align__(16) float arow[DDIM];
  for (int k = c; k < DDIM; k += 128) arow[k] = imgn[(size_t)m * DDIM + k];
  __syncthreads();
  const float4* br = (const float4*)(txtn + (size_t)c * DDIM);
  const float4* ar = (const float4*)arow;
  float dot = 0.f;
  #pragma unroll 8
  for (int k = 0; k < DDIM/4; ++k) {
    float4 x = ar[k], y = br[k];
    dot += x.x*y.x + x.y*y.y + x.z*y.z + x.w*y.w;
  }
  float t = expf(fminf(fmaxf(sc[0], -10.f), 10.f));
  float logit = fminf(fmaxf(t*dot + bi[0], -50.f), 50.f);
  float x = (c == m) ? logit : -logit;
  float v = neg_log_sigmoid(x);
  __shared__ float sb[2];
  #pragma unroll
  for (int o = 32; o; o >>= 1) v += __shfl_down(v, o);
  if ((c & 63) == 0) sb[c >> 6] = v;
  __syncthreads();
  if (c == 0) atomicAdd(acc, sb[0] + sb[1]);
}

__global__ void rc_loss_kernel(const int* __restrict__ Max, const int* __restrict__ counts,
                               const float* __restrict__ sc, const float* __restrict__ bi,
                               float* __restrict__ acc) {
  int m = blockIdx.x;
  int v = threadIdx.x;  // 128 threads
  const int* row = Max + (size_t)m * NCOLS + (size_t)v * WCON;
  int cnt = counts[v];
  float s = 0.f;
  for (int w = 0; w < cnt; ++w) s += decf(row[w]);
  float S = s / (float)cnt;
  float t = expf(fminf(fmaxf(sc[0], -10.f), 10.f));
  float logit = fminf(fmaxf(t*S + bi[0], -50.f), 50.f);
  float x = (v == m) ? logit : -logit;
  float val = neg_log_sigmoid(x);
  __shared__ float sb[2];
  #pragma unroll
  for (int o = 32; o; o >>= 1) val += __shfl_down(val, o);
  if ((v & 63) == 0) sb[v >> 6] = val;
  __syncthreads();
  if (v == 0) atomicAdd(acc, sb[0] + sb[1]);
}

__global__ void finalize_kernel(const float* __restrict__ acc, float* __restrict__ out) {
  if (threadIdx.x == 0 && blockIdx.x == 0) {
    float it = acc[0] * (1.f / 16384.f);
    float rc = acc[1] * (1.f / 16384.f);
    out[0] = it + 0.5f * rc;
    out[1] = it;
    out[2] = rc;
  }
}

// ---------------- launch ----------------

extern "C" void kernel_launch(void* const* d_in, const int* in_sizes, int n_in,
                              void* d_out, int out_size, void* d_ws, size_t ws_size,
                              hipStream_t stream) {
  const float* image_features        = (const float*)d_in[0];
  const float* text_features         = (const float*)d_in[1];
  const float* image_token_features  = (const float*)d_in[2];
  const float* concept_text_features = (const float*)d_in[3];
  const int*   concept_counts        = (const int*)d_in[4];
  const float* logit_scale           = (const float*)d_in[5];
  const float* logit_bias            = (const float*)d_in[6];
  float* out = (float*)d_out;

  if (ws_size < WS_NEED) {
    hipMemsetAsync(d_out, 0, (size_t)out_size * sizeof(float), stream);
    return;
  }

  char* ws = (char*)d_ws;
  char*  patches_i8  = ws + PI8_OFF;
  char*  concepts_i8 = ws + CI8_OFF;
  float* sp          = (float*)(ws + SP_OFF);
  float* scq         = (float*)(ws + SC_OFF);
  float* imgn        = (float*)(ws + IMGN_OFF);
  float* txtn        = (float*)(ws + TXTN_OFF);
  int*   Maxbuf      = (int*)(ws + MAX_OFF);
  float* acc         = (float*)(ws + ACC_OFF);

  hipMemsetAsync(acc, 0, 2 * sizeof(float), stream);
  hipMemsetAsync(Maxbuf, 0x80, MAX_BYTES, stream);  // decodes to very negative

  norm_f32_kernel<<<BATCH, 192, 0, stream>>>(image_features, imgn);
  norm_f32_kernel<<<BATCH, 192, 0, stream>>>(text_features, txtn);
  norm_quant_i8<<<MTOT, 192, 0, stream>>>(image_token_features, patches_i8, sp);
  norm_quant_i8<<<NCOLS, 192, 0, stream>>>(concept_text_features, concepts_i8, scq);

  rc_gemm_max_kernel<<<NBLK, 256, 0, stream>>>(patches_i8, concepts_i8, sp, scq, Maxbuf);

  it_loss_kernel<<<BATCH, 128, 0, stream>>>(imgn, txtn, logit_scale, logit_bias, acc);
  rc_loss_kernel<<<BATCH, 128, 0, stream>>>(Maxbuf, concept_counts, logit_scale, logit_bias, acc + 1);
  finalize_kernel<<<1, 64, 0, stream>>>(acc, out);
}

// Round 6
// 161.159 us; speedup vs baseline: 1.7765x; 1.0539x over previous
//
#include <hip/hip_runtime.h>
#include <hip/hip_bf16.h>
#include <cstdint>

using i32x4 = __attribute__((ext_vector_type(4))) int;

// Problem dims
#define BATCH   128
#define NPATCH  196
#define MTOT    25088   // 128*196, = 98*256 exactly
#define MT      98      // M-tiles of 256
#define DDIM    768
#define WCON    32
#define NCOLS   4096    // BATCH*WCON
#define BNC     128     // cols per block
#define NBN     32      // NCOLS/BNC
#define NT      12      // K-tiles of 64
#define NBLK    3136    // MT*NBN

// ws layout (bytes), each 256-aligned
#define PI8_OFF   0ull
#define PI8_BYTES ((size_t)MTOT*DDIM)          // 19.3 MB
#define CI8_OFF   (PI8_OFF + PI8_BYTES)
#define CI8_BYTES (4096ull*DDIM)               // 3.1 MB
#define SP_OFF    (CI8_OFF + CI8_BYTES)
#define SP_BYTES  ((size_t)MTOT*4)
#define SC_OFF    (SP_OFF + SP_BYTES)
#define SC_BYTES  (4096ull*4)
#define IMGN_OFF  (SC_OFF + SC_BYTES)
#define F_BYTES   (128ull*768*4)
#define TXTN_OFF  (IMGN_OFF + F_BYTES)
#define MAX_OFF   (TXTN_OFF + F_BYTES)
#define MAX_BYTES (128ull*4096*4)
#define ACC_OFF   (MAX_OFF + MAX_BYTES)
#define WS_NEED   (ACC_OFF + 256ull)

__device__ __forceinline__ void async_cp16(void* lds, const void* g) {
  __builtin_amdgcn_global_load_lds(
      (const __attribute__((address_space(1))) unsigned int*)g,
      (__attribute__((address_space(3))) unsigned int*)lds, 16, 0, 0);
}

__device__ __forceinline__ float neg_log_sigmoid(float x) {
  return (x > 0.f) ? log1pf(expf(-x)) : (log1pf(expf(x)) - x);
}

// monotone float<->int encoding for atomicMax on floats (no NaNs here)
__device__ __forceinline__ int encf(float f) {
  int i = __float_as_int(f);
  return i >= 0 ? i : (i ^ 0x7FFFFFFF);
}
__device__ __forceinline__ float decf(int e) {
  return __int_as_float(e >= 0 ? e : (e ^ 0x7FFFFFFF));
}

template<int VM>
__device__ __forceinline__ void vmwait() {
  asm volatile("s_waitcnt vmcnt(%0)" :: "n"(VM) : "memory");
}
__device__ __forceinline__ void blockbar() {
  asm volatile("" ::: "memory");
  __builtin_amdgcn_s_barrier();
  asm volatile("" ::: "memory");
}

// ---------------- normalization kernels ----------------

// f32-normalized rows for the IT path
__global__ void norm_f32_kernel(const float* __restrict__ in, float* __restrict__ out) {
  int row = blockIdx.x;
  int t = threadIdx.x; // 0..191
  const float4* ir = (const float4*)(in + (size_t)row * DDIM);
  float4 v = ir[t];
  float ss = v.x*v.x + v.y*v.y + v.z*v.z + v.w*v.w;
  __shared__ float sb[3];
  #pragma unroll
  for (int o = 32; o; o >>= 1) ss += __shfl_down(ss, o);
  if ((t & 63) == 0) sb[t >> 6] = ss;
  __syncthreads();
  float tot = sb[0] + sb[1] + sb[2];
  float scale = 1.0f / fmaxf(sqrtf(tot), 1e-12f);
  ((float4*)(out + (size_t)row * DDIM))[t] =
      make_float4(v.x*scale, v.y*scale, v.z*scale, v.w*scale);
}

// per-row: normalize + symmetric-absmax int8 quantization.
// q_k = rint(127 * x_k / absmax(x)); dequant scale srow = absmax / (127 * ||x||)
__global__ void norm_quant_i8(const float* __restrict__ in, char* __restrict__ out,
                              float* __restrict__ srow) {
  int row = blockIdx.x;
  int t = threadIdx.x; // 0..191
  const float4* ir = (const float4*)(in + (size_t)row * DDIM);
  float4 v = ir[t];
  float ss = v.x*v.x + v.y*v.y + v.z*v.z + v.w*v.w;
  float am = fmaxf(fmaxf(fabsf(v.x), fabsf(v.y)), fmaxf(fabsf(v.z), fabsf(v.w)));
  __shared__ float sbs[3], sba[3];
  #pragma unroll
  for (int o = 32; o; o >>= 1) {
    ss += __shfl_down(ss, o);
    am = fmaxf(am, __shfl_down(am, o));
  }
  if ((t & 63) == 0) { sbs[t >> 6] = ss; sba[t >> 6] = am; }
  __syncthreads();
  float tot = sbs[0] + sbs[1] + sbs[2];
  float amx = fmaxf(fmaxf(sba[0], sba[1]), fmaxf(sba[2], 1e-30f));
  float qs = 127.0f / amx;
  int qx = (int)rintf(v.x * qs), qy = (int)rintf(v.y * qs);
  int qz = (int)rintf(v.z * qs), qw = (int)rintf(v.w * qs);
  uint packed = (uint)(qx & 0xff) | ((uint)(qy & 0xff) << 8) |
                ((uint)(qz & 0xff) << 16) | ((uint)(qw & 0xff) << 24);
  ((uint*)(out + (size_t)row * DDIM))[t] = packed;
  if (t == 0) srow[row] = amx / (127.0f * fmaxf(sqrtf(tot), 1e-12f));
}

// ---------------- RC GEMM (int8) + column max ----------------
// Packed A: 25088x768 i8. Grid 98 M-tiles x 32 N-tiles.
// 256 threads, 4 waves (2M x 2N), wave tile 128x64. BK=64, 12 K-tiles.
// 3-deep LDS pipeline (3 x 24KB), counted vmcnt(12), raw s_barrier —
// no vmcnt(0) drain inside the loop; ~2 tiles of prefetch slack.
__global__ __launch_bounds__(256, 2)
void rc_gemm_max_kernel(const char* __restrict__ patches,
                        const char* __restrict__ concepts,
                        const float* __restrict__ sp,
                        const float* __restrict__ sc,
                        int* __restrict__ Max) {
  __shared__ __align__(16) char lds[3 * 24576];
  __shared__ float sp_lds[256];
  __shared__ float sc_lds[128];
  __shared__ float colmax[2][2][128];   // [wm][seg][col]

  const int bid0 = blockIdx.x;
  const int lin = (bid0 & 7) * 392 + (bid0 >> 3);  // bijective (3136 = 8*392)
  const int mt = lin >> 5;          // mt-major within XCD: B stays L2-hot
  const int bn = lin & 31;
  const int tid = threadIdx.x;
  const int lane = tid & 63;
  const int wid = tid >> 6;
  const int wm = wid >> 1;   // 0..1
  const int wn = wid & 1;    // 0..1
  const int brow = mt * 256;
  const int bcol = bn * BNC;

  const char* Ab = patches  + (size_t)brow * DDIM;
  const char* Bb = concepts + (size_t)bcol * DDIM;

  // epilogue scales into LDS (used after many syncs)
  sp_lds[tid] = sp[brow + tid];
  if (tid < 128) sc_lds[tid] = sc[bcol + tid];

  // swizzled ds_read byte offsets (rows of 64B, 4 chunks of 16B, quad-XOR)
  int a_off[8], b_off[4];
  #pragma unroll
  for (int i = 0; i < 8; ++i) {
    int row = wm*128 + i*16 + (lane & 15);
    int slot = (lane >> 4) ^ ((row >> 1) & 3);
    a_off[i] = row*64 + slot*16;
  }
  #pragma unroll
  for (int j = 0; j < 4; ++j) {
    int col = wn*64 + j*16 + (lane & 15);
    int slot = (lane >> 4) ^ ((col >> 1) & 3);
    b_off[j] = 16384 + col*64 + slot*16;
  }

  i32x4 acc[8][4];
  #pragma unroll
  for (int i = 0; i < 8; ++i)
    #pragma unroll
    for (int j = 0; j < 4; ++j) {
      i32x4 z = {0, 0, 0, 0};
      acc[i][j] = z;
    }

  // stage K-tile t into explicit buffer: A 16KB (4 chunks/thr), B 8KB (2 chunks/thr)
  auto stage = [&](int t, int bufi) {
    char* dst = lds + bufi * 24576;
    const int kcol = t * 64;
    #pragma unroll
    for (int k2 = 0; k2 < 4; ++k2) {
      int c = tid + k2*256;
      int r = c >> 2;
      int q = (c & 3) ^ ((r >> 1) & 3);
      async_cp16(dst + c*16, Ab + (size_t)r*DDIM + kcol + q*16);
    }
    #pragma unroll
    for (int k2 = 0; k2 < 2; ++k2) {
      int c = tid + k2*256;
      int r = c >> 2;
      int q = (c & 3) ^ ((r >> 1) & 3);
      async_cp16(dst + 16384 + c*16, Bb + (size_t)r*DDIM + kcol + q*16);
    }
  };

  auto compute = [&](int bufi) {
    const char* ab = lds + bufi * 24576;
    i32x4 a[8], b[4];
    #pragma unroll
    for (int i = 0; i < 8; ++i) a[i] = *(const i32x4*)(ab + a_off[i]);
    #pragma unroll
    for (int j = 0; j < 4; ++j) b[j] = *(const i32x4*)(ab + b_off[j]);
    __builtin_amdgcn_s_setprio(1);
    #pragma unroll
    for (int i = 0; i < 8; ++i)
      #pragma unroll
      for (int j = 0; j < 4; ++j)
        acc[i][j] = __builtin_amdgcn_mfma_i32_16x16x64_i8(a[i], b[j], acc[i][j], 0, 0, 0);
    __builtin_amdgcn_s_setprio(0);
  };

  // TILE: stage t+2 (buf (t+2)%3), wait tile t landed (counted), compute t.
  // End barrier: all waves done reading buf t%3 before it's restaged at t+3.
#define TILE(T, VMN, DOSTAGE)                                                 \
  {                                                                           \
    if (DOSTAGE) stage((T) + 2, ((T) + 2) % 3);                               \
    vmwait<VMN>();                                                            \
    blockbar();                                                               \
    compute((T) % 3);                                                         \
    blockbar();                                                               \
  }

  stage(0, 0);
  stage(1, 1);
  TILE(0, 12, 1)  TILE(1, 12, 1)  TILE(2, 12, 1)  TILE(3, 12, 1)
  TILE(4, 12, 1)  TILE(5, 12, 1)  TILE(6, 12, 1)  TILE(7, 12, 1)
  TILE(8, 12, 1)  TILE(9, 12, 1)  TILE(10, 6, 0)  TILE(11, 0, 0)
#undef TILE

  // epilogue: dequant + segmented column max (wave's 128 rows span <= 2 images)
  float cmax[4][2];
  #pragma unroll
  for (int j = 0; j < 4; ++j) { cmax[j][0] = -3e38f; cmax[j][1] = -3e38f; }
  float scv[4];
  #pragma unroll
  for (int j = 0; j < 4; ++j) scv[j] = sc_lds[wn*64 + j*16 + (lane & 15)];
  const int img0w = (brow + wm*128) / NPATCH;
  #pragma unroll
  for (int i = 0; i < 8; ++i) {
    #pragma unroll
    for (int e = 0; e < 4; ++e) {
      int rl = wm*128 + i*16 + (lane >> 4)*4 + e;
      float spv = sp_lds[rl];
      int seg = ((brow + rl) / NPATCH) - img0w;   // 0 or 1
      #pragma unroll
      for (int j = 0; j < 4; ++j) {
        float v = (float)acc[i][j][e] * spv * scv[j];
        cmax[j][0] = (seg == 0) ? fmaxf(cmax[j][0], v) : cmax[j][0];
        cmax[j][1] = (seg == 1) ? fmaxf(cmax[j][1], v) : cmax[j][1];
      }
    }
  }
  #pragma unroll
  for (int j = 0; j < 4; ++j) {
    #pragma unroll
    for (int s = 0; s < 2; ++s) {
      float v = cmax[j][s];
      v = fmaxf(v, __shfl_xor(v, 16));
      v = fmaxf(v, __shfl_xor(v, 32));
      cmax[j][s] = v;
    }
  }
  if (lane < 16) {
    #pragma unroll
    for (int j = 0; j < 4; ++j) {
      colmax[wm][0][wn*64 + j*16 + lane] = cmax[j][0];
      colmax[wm][1][wn*64 + j*16 + lane] = cmax[j][1];
    }
  }
  __syncthreads();
  {
    int w = tid >> 7;          // 0..1 (wm)
    int col = tid & 127;
    int i0 = (brow + w*128) / NPATCH;
    int i1 = (brow + w*128 + 127) / NPATCH;
    int gcol = bcol + col;
    atomicMax(&Max[(size_t)i0 * NCOLS + gcol], encf(colmax[w][0][col]));
    if (i1 != i0) atomicMax(&Max[(size_t)i1 * NCOLS + gcol], encf(colmax[w][1][col]));
  }
}

// ---------------- losses ----------------

__global__ void it_loss_kernel(const float* __restrict__ imgn, const float* __restrict__ txtn,
                               const float* __restrict__ sc, const float* __restrict__ bi,
                               float* __restrict__ acc) {
  int m = blockIdx.x;
  int c = threadIdx.x;  // 128 threads
  __shared__ __align__(16) float arow[DDIM];
  for (int k = c; k < DDIM; k += 128) arow[k] = imgn[(size_t)m * DDIM + k];
  __syncthreads();
  const float4* br = (const float4*)(txtn + (size_t)c * DDIM);
  const float4* ar = (const float4*)arow;
  float dot = 0.f;
  #pragma unroll 8
  for (int k = 0; k < DDIM/4; ++k) {
    float4 x = ar[k], y = br[k];
    dot += x.x*y.x + x.y*y.y + x.z*y.z + x.w*y.w;
  }
  float t = expf(fminf(fmaxf(sc[0], -10.f), 10.f));
  float logit = fminf(fmaxf(t*dot + bi[0], -50.f), 50.f);
  float x = (c == m) ? logit : -logit;
  float v = neg_log_sigmoid(x);
  __shared__ float sb[2];
  #pragma unroll
  for (int o = 32; o; o >>= 1) v += __shfl_down(v, o);
  if ((c & 63) == 0) sb[c >> 6] = v;
  __syncthreads();
  if (c == 0) atomicAdd(acc, sb[0] + sb[1]);
}

__global__ void rc_loss_kernel(const int* __restrict__ Max, const int* __restrict__ counts,
                               const float* __restrict__ sc, const float* __restrict__ bi,
                               float* __restrict__ acc) {
  int m = blockIdx.x;
  int v = threadIdx.x;  // 128 threads
  const int* row = Max + (size_t)m * NCOLS + (size_t)v * WCON;
  int cnt = counts[v];
  float s = 0.f;
  for (int w = 0; w < cnt; ++w) s += decf(row[w]);
  float S = s / (float)cnt;
  float t = expf(fminf(fmaxf(sc[0], -10.f), 10.f));
  float logit = fminf(fmaxf(t*S + bi[0], -50.f), 50.f);
  float x = (v == m) ? logit : -logit;
  float val = neg_log_sigmoid(x);
  __shared__ float sb[2];
  #pragma unroll
  for (int o = 32; o; o >>= 1) val += __shfl_down(val, o);
  if ((v & 63) == 0) sb[v >> 6] = val;
  __syncthreads();
  if (v == 0) atomicAdd(acc, sb[0] + sb[1]);
}

__global__ void finalize_kernel(const float* __restrict__ acc, float* __restrict__ out) {
  if (threadIdx.x == 0 && blockIdx.x == 0) {
    float it = acc[0] * (1.f / 16384.f);
    float rc = acc[1] * (1.f / 16384.f);
    out[0] = it + 0.5f * rc;
    out[1] = it;
    out[2] = rc;
  }
}

// ---------------- launch ----------------

extern "C" void kernel_launch(void* const* d_in, const int* in_sizes, int n_in,
                              void* d_out, int out_size, void* d_ws, size_t ws_size,
                              hipStream_t stream) {
  const float* image_features        = (const float*)d_in[0];
  const float* text_features         = (const float*)d_in[1];
  const float* image_token_features  = (const float*)d_in[2];
  const float* concept_text_features = (const float*)d_in[3];
  const int*   concept_counts        = (const int*)d_in[4];
  const float* logit_scale           = (const float*)d_in[5];
  const float* logit_bias            = (const float*)d_in[6];
  float* out = (float*)d_out;

  if (ws_size < WS_NEED) {
    hipMemsetAsync(d_out, 0, (size_t)out_size * sizeof(float), stream);
    return;
  }

  char* ws = (char*)d_ws;
  char*  patches_i8  = ws + PI8_OFF;
  char*  concepts_i8 = ws + CI8_OFF;
  float* sp          = (float*)(ws + SP_OFF);
  float* scq         = (float*)(ws + SC_OFF);
  float* imgn        = (float*)(ws + IMGN_OFF);
  float* txtn        = (float*)(ws + TXTN_OFF);
  int*   Maxbuf      = (int*)(ws + MAX_OFF);
  float* acc         = (float*)(ws + ACC_OFF);

  hipMemsetAsync(acc, 0, 2 * sizeof(float), stream);
  hipMemsetAsync(Maxbuf, 0x80, MAX_BYTES, stream);  // decodes to very negative

  norm_f32_kernel<<<BATCH, 192, 0, stream>>>(image_features, imgn);
  norm_f32_kernel<<<BATCH, 192, 0, stream>>>(text_features, txtn);
  norm_quant_i8<<<MTOT, 192, 0, stream>>>(image_token_features, patches_i8, sp);
  norm_quant_i8<<<NCOLS, 192, 0, stream>>>(concept_text_features, concepts_i8, scq);

  rc_gemm_max_kernel<<<NBLK, 256, 0, stream>>>(patches_i8, concepts_i8, sp, scq, Maxbuf);

  it_loss_kernel<<<BATCH, 128, 0, stream>>>(imgn, txtn, logit_scale, logit_bias, acc);
  rc_loss_kernel<<<BATCH, 128, 0, stream>>>(Maxbuf, concept_counts, logit_scale, logit_bias, acc + 1);
  finalize_kernel<<<1, 64, 0, stream>>>(acc, out);
}